// Round 2
// baseline (630.195 us; speedup 1.0000x reference)
//
#include <hip/hip_runtime.h>

// Problem constants
#define B_N 4096
#define T_N 512
// Output layout (floats): final (B,T,2) | fwd_out (B,2) | noise (B,T,1)
#define FWD_OFF   (B_N * T_N * 2)        // 4194304
#define NOISE_OFF (FWD_OFF + B_N * 2)    // 4202496
// Workspace layout (floats): encoder final states
#define WS_H0 0
#define WS_C0 (B_N * 4)
#define WS_H1 (B_N * 8)
#define WS_C1 (B_N * 12)

// Force a value to live in a VGPR; origin becomes opaque so the compiler
// cannot re-materialize the load inside the time loop.
#define KEEPF(x) asm volatile("" : "+v"(x))

#define S_SIG  (-1.4426950408889634f)   // -log2(e)
#define S_TANH (-2.8853900817779268f)   // -2*log2(e)

// Gate accumulator already carries the -log2e (or -2log2e) scale:
__device__ __forceinline__ float sig_acc(float a) {
    // sigmoid(v) where a = -log2e * v
    return __builtin_amdgcn_rcpf(1.0f + exp2f(a));
}
__device__ __forceinline__ float tanh_acc(float a) {
    // tanh(v) where a = -2*log2e * v
    return fmaf(2.0f, __builtin_amdgcn_rcpf(1.0f + exp2f(a)), -1.0f);
}
__device__ __forceinline__ float tanh_nat(float v) {
    return tanh_acc(v * S_TANH);
}

// ---------------- Encoder: 4 lanes per batch element (unit-major, H=4) ----------------
__global__ __launch_bounds__(256, 1) void enc_kernel(
    const float* __restrict__ x,
    const float* __restrict__ Wih0, const float* __restrict__ Whh0,
    const float* __restrict__ bih0, const float* __restrict__ bhh0,
    const float* __restrict__ Wih1, const float* __restrict__ Whh1,
    const float* __restrict__ bih1, const float* __restrict__ bhh1,
    const float* __restrict__ fcW, const float* __restrict__ fcb,
    float* __restrict__ out, float* __restrict__ ws)
{
    const int tid = blockIdx.x * 256 + threadIdx.x;
    const int b = tid >> 2;   // batch element
    const int u = tid & 3;    // hidden unit

    // Per-lane weights, pre-scaled for exp2-based activations.
    float wih0r[4], b0r[4], b1r[4];
    float whh0r[4][4], wih1r[4][4], whh1r[4][4];
#pragma unroll
    for (int k = 0; k < 4; ++k) {
        const int r = k * 4 + u;
        const float sc = (k == 2) ? S_TANH : S_SIG;
        wih0r[k] = Wih0[r] * sc;
        b0r[k] = (bih0[r] + bhh0[r]) * sc;
        b1r[k] = (bih1[r] + bhh1[r]) * sc;
#pragma unroll
        for (int j = 0; j < 4; ++j) {
            whh0r[k][j] = Whh0[r * 4 + j] * sc;
            wih1r[k][j] = Wih1[r * 4 + j] * sc;
            whh1r[k][j] = Whh1[r * 4 + j] * sc;
        }
    }
#pragma unroll
    for (int k = 0; k < 4; ++k) {
        KEEPF(wih0r[k]); KEEPF(b0r[k]); KEEPF(b1r[k]);
#pragma unroll
        for (int j = 0; j < 4; ++j) {
            KEEPF(whh0r[k][j]); KEEPF(wih1r[k][j]); KEEPF(whh1r[k][j]);
        }
    }

    float h0v[4] = {0.f, 0.f, 0.f, 0.f};
    float h1v[4] = {0.f, 0.f, 0.f, 0.f};
    float c0 = 0.f, c1 = 0.f, h0u = 0.f, h1u = 0.f;

    const float4* __restrict__ xq4 = (const float4*)(x + (long)b * T_N);
    float4 xq = xq4[0];

    auto step = [&](float xc) {
        // L1 partial from previous h1 (independent of L0 chain -> ILP)
        float p1[4];
#pragma unroll
        for (int k = 0; k < 4; ++k) {
            p1[k] = b1r[k];
#pragma unroll
            for (int j = 0; j < 4; ++j) p1[k] = fmaf(whh1r[k][j], h1v[j], p1[k]);
        }
        // L0 gates (accumulators are pre-scaled)
        float g[4];
#pragma unroll
        for (int k = 0; k < 4; ++k) {
            g[k] = fmaf(wih0r[k], xc, b0r[k]);
#pragma unroll
            for (int j = 0; j < 4; ++j) g[k] = fmaf(whh0r[k][j], h0v[j], g[k]);
        }
        float iv = sig_acc(g[0]), fv = sig_acc(g[1]), gv = tanh_acc(g[2]), ov = sig_acc(g[3]);
        c0 = fmaf(fv, c0, iv * gv);
        h0u = ov * tanh_nat(c0);
#pragma unroll
        for (int j = 0; j < 4; ++j) h0v[j] = __shfl(h0u, j, 4);

        // L1 gates
#pragma unroll
        for (int k = 0; k < 4; ++k) {
#pragma unroll
            for (int j = 0; j < 4; ++j) p1[k] = fmaf(wih1r[k][j], h0v[j], p1[k]);
        }
        iv = sig_acc(p1[0]); fv = sig_acc(p1[1]); gv = tanh_acc(p1[2]); ov = sig_acc(p1[3]);
        c1 = fmaf(fv, c1, iv * gv);
        h1u = ov * tanh_nat(c1);
#pragma unroll
        for (int j = 0; j < 4; ++j) h1v[j] = __shfl(h1u, j, 4);
    };

    for (int tb = 0; tb < T_N / 4; ++tb) {
        float4 xn = (tb + 1 < T_N / 4) ? xq4[tb + 1] : xq;  // prefetch next quad
        step(xq.x); step(xq.y); step(xq.z); step(xq.w);
        xq = xn;
    }

    // Final states for the decoder
    ws[WS_H0 + b * 4 + u] = h0u;
    ws[WS_C0 + b * 4 + u] = c0;
    ws[WS_H1 + b * 4 + u] = h1u;
    ws[WS_C1 + b * 4 + u] = c1;

    // fwd_out = h1 @ fc_W.T + fc_b  (2 outputs, lanes 0/1)
    if (u < 2) {
        float fw = fcb[u];
#pragma unroll
        for (int j = 0; j < 4; ++j) fw = fmaf(fcW[u * 4 + j], h1v[j], fw);
        out[FWD_OFF + b * 2 + u] = fw;
    }
}

// ---------------- Decoder: 16 lanes per batch element (unit-major, H=10) ----------------
__global__ __launch_bounds__(256, 1) void dec_kernel(
    const float* __restrict__ Wih0, const float* __restrict__ Whh0,
    const float* __restrict__ bih0, const float* __restrict__ bhh0,
    const float* __restrict__ Wih1, const float* __restrict__ Whh1,
    const float* __restrict__ bih1, const float* __restrict__ bhh1,
    const float* __restrict__ outW, const float* __restrict__ outb,
    float* __restrict__ out, const float* __restrict__ ws)
{
    const int tid = blockIdx.x * 256 + threadIdx.x;
    const int b = tid >> 4;        // batch element
    const int u = tid & 15;        // unit (0..9 active; 10..15 shadow unit 9)
    const int uc = (u < 10) ? u : 9;

    float wih0r[4], b0r[4], b1r[4];
    float whh0r[4][10], wih1r[4][10], whh1r[4][10];
#pragma unroll
    for (int k = 0; k < 4; ++k) {
        const int r = k * 10 + uc;
        const float sc = (k == 2) ? S_TANH : S_SIG;
        wih0r[k] = Wih0[r] * sc;
        b0r[k] = (bih0[r] + bhh0[r]) * sc;
        b1r[k] = (bih1[r] + bhh1[r]) * sc;
#pragma unroll
        for (int j = 0; j < 10; ++j) {
            whh0r[k][j] = Whh0[r * 10 + j] * sc;
            wih1r[k][j] = Wih1[r * 10 + j] * sc;
            whh1r[k][j] = Whh1[r * 10 + j] * sc;
        }
    }
    float outw[10];
#pragma unroll
    for (int j = 0; j < 10; ++j) outw[j] = outW[j];
    float outb0 = outb[0];
    float fwd0 = out[FWD_OFF + b * 2 + 0];
    float fwd1 = out[FWD_OFF + b * 2 + 1];

    // Pin everything loop-invariant into VGPRs (compiler was re-loading
    // per step: VGPR_Count was 88 << 145 resident floats needed).
#pragma unroll
    for (int k = 0; k < 4; ++k) {
        KEEPF(wih0r[k]); KEEPF(b0r[k]); KEEPF(b1r[k]);
#pragma unroll
        for (int j = 0; j < 10; ++j) {
            KEEPF(whh0r[k][j]); KEEPF(wih1r[k][j]); KEEPF(whh1r[k][j]);
        }
    }
#pragma unroll
    for (int j = 0; j < 10; ++j) KEEPF(outw[j]);
    KEEPF(outb0); KEEPF(fwd0); KEEPF(fwd1);

    // Initial states: encoder finals padded 4 -> 10 with zeros
    float h0v[10], h1v[10];
#pragma unroll
    for (int j = 0; j < 10; ++j) {
        h0v[j] = (j < 4) ? ws[WS_H0 + b * 4 + j] : 0.f;
        h1v[j] = (j < 4) ? ws[WS_H1 + b * 4 + j] : 0.f;
    }
    float c0 = (u < 4) ? ws[WS_C0 + b * 4 + u] : 0.f;
    float c1 = (u < 4) ? ws[WS_C1 + b * 4 + u] : 0.f;

    float my_noise = 0.f;

    for (int t = 0; t < T_N; ++t) {
        const float inp = h1v[0];

        // L1 partial from previous h1 (independent of L0 chain)
        float p1[4];
#pragma unroll
        for (int k = 0; k < 4; ++k) {
            p1[k] = b1r[k];
#pragma unroll
            for (int j = 0; j < 10; ++j) p1[k] = fmaf(whh1r[k][j], h1v[j], p1[k]);
        }

        // L0 gates
        float g[4];
#pragma unroll
        for (int k = 0; k < 4; ++k) {
            g[k] = fmaf(wih0r[k], inp, b0r[k]);
#pragma unroll
            for (int j = 0; j < 10; ++j) g[k] = fmaf(whh0r[k][j], h0v[j], g[k]);
        }
        float iv = sig_acc(g[0]), fv = sig_acc(g[1]), gv = tanh_acc(g[2]), ov = sig_acc(g[3]);
        c0 = fmaf(fv, c0, iv * gv);
        const float h0u = ov * tanh_nat(c0);
#pragma unroll
        for (int j = 0; j < 10; ++j) h0v[j] = __shfl(h0u, j, 16);

        // L1 gates
#pragma unroll
        for (int k = 0; k < 4; ++k) {
#pragma unroll
            for (int j = 0; j < 10; ++j) p1[k] = fmaf(wih1r[k][j], h0v[j], p1[k]);
        }
        iv = sig_acc(p1[0]); fv = sig_acc(p1[1]); gv = tanh_acc(p1[2]); ov = sig_acc(p1[3]);
        c1 = fmaf(fv, c1, iv * gv);
        const float h1u = ov * tanh_nat(c1);
#pragma unroll
        for (int j = 0; j < 10; ++j) h1v[j] = __shfl(h1u, j, 16);

        // noise_t = dec_out . out_W + out_b (replicated on all 16 lanes)
        float nz = outb0;
#pragma unroll
        for (int j = 0; j < 10; ++j) nz = fmaf(outw[j], h1v[j], nz);

        // lane u keeps the t with t%16==u; flush coalesced every 16 steps
        my_noise = ((t & 15) == u) ? nz : my_noise;
        if ((t & 15) == 15) {
            const int idx = b * T_N + (t - 15) + u;
            out[NOISE_OFF + idx] = my_noise;
            out[2 * idx + 0] = my_noise + fwd0;
            out[2 * idx + 1] = my_noise + fwd1;
        }
    }
}

extern "C" void kernel_launch(void* const* d_in, const int* in_sizes, int n_in,
                              void* d_out, int out_size, void* d_ws, size_t ws_size,
                              hipStream_t stream) {
    const float* x        = (const float*)d_in[0];
    // d_in[1] = context (unused by the reference)
    const float* eWih0 = (const float*)d_in[2];
    const float* eWhh0 = (const float*)d_in[3];
    const float* ebih0 = (const float*)d_in[4];
    const float* ebhh0 = (const float*)d_in[5];
    const float* eWih1 = (const float*)d_in[6];
    const float* eWhh1 = (const float*)d_in[7];
    const float* ebih1 = (const float*)d_in[8];
    const float* ebhh1 = (const float*)d_in[9];
    const float* dWih0 = (const float*)d_in[10];
    const float* dWhh0 = (const float*)d_in[11];
    const float* dbih0 = (const float*)d_in[12];
    const float* dbhh0 = (const float*)d_in[13];
    const float* dWih1 = (const float*)d_in[14];
    const float* dWhh1 = (const float*)d_in[15];
    const float* dbih1 = (const float*)d_in[16];
    const float* dbhh1 = (const float*)d_in[17];
    const float* fcW   = (const float*)d_in[18];
    const float* fcb   = (const float*)d_in[19];
    const float* outW  = (const float*)d_in[20];
    const float* outb  = (const float*)d_in[21];

    float* out = (float*)d_out;
    float* ws  = (float*)d_ws;

    // Encoder: 4096 elems x 4 lanes = 16384 threads
    enc_kernel<<<dim3((B_N * 4) / 256), dim3(256), 0, stream>>>(
        x, eWih0, eWhh0, ebih0, ebhh0, eWih1, eWhh1, ebih1, ebhh1,
        fcW, fcb, out, ws);

    // Decoder: 4096 elems x 16 lanes = 65536 threads
    dec_kernel<<<dim3((B_N * 16) / 256), dim3(256), 0, stream>>>(
        dWih0, dWhh0, dbih0, dbhh0, dWih1, dWhh1, dbih1, dbhh1,
        outW, outb, out, ws);
}

// Round 3
// 471.380 us; speedup vs baseline: 1.3369x; 1.3369x over previous
//
#include <hip/hip_runtime.h>

// Problem constants
#define B_N 4096
#define T_N 512
// Output layout (floats): final (B,T,2) | fwd_out (B,2) | noise (B,T,1)
#define FWD_OFF   (B_N * T_N * 2)        // 4194304
#define NOISE_OFF (FWD_OFF + B_N * 2)    // 4202496

#define S_SIG  (-1.4426950408889634f)   // -log2(e)
#define S_TANH (-2.8853900817779268f)   // -2*log2(e)

// act on pre-scaled accumulator: returns fma(A, rcp(1+exp2(a)), B)
// A=1,B=0  -> sigmoid(v) where a = -log2e*v
// A=2,B=-1 -> tanh(v)    where a = -2log2e*v
__device__ __forceinline__ float act_ab(float a, float A, float Bc) {
    float r = __builtin_amdgcn_rcpf(1.0f + __builtin_amdgcn_exp2f(a));
    return fmaf(A, r, Bc);
}
__device__ __forceinline__ float sig_acc(float a) {
    return __builtin_amdgcn_rcpf(1.0f + __builtin_amdgcn_exp2f(a));
}
__device__ __forceinline__ float tanh_acc(float a) {
    return fmaf(2.0f, __builtin_amdgcn_rcpf(1.0f + __builtin_amdgcn_exp2f(a)), -1.0f);
}
__device__ __forceinline__ float tanh_nat(float v) {
    return tanh_acc(v * S_TANH);
}

__global__ __attribute__((amdgpu_waves_per_eu(1, 1))) __launch_bounds__(256)
void fused_kernel(
    const float* __restrict__ x,
    const float* __restrict__ eWih0, const float* __restrict__ eWhh0,
    const float* __restrict__ ebih0, const float* __restrict__ ebhh0,
    const float* __restrict__ eWih1, const float* __restrict__ eWhh1,
    const float* __restrict__ ebih1, const float* __restrict__ ebhh1,
    const float* __restrict__ dWih0, const float* __restrict__ dWhh0,
    const float* __restrict__ dbih0, const float* __restrict__ dbhh0,
    const float* __restrict__ dWih1, const float* __restrict__ dWhh1,
    const float* __restrict__ dbih1, const float* __restrict__ dbhh1,
    const float* __restrict__ fcW, const float* __restrict__ fcb,
    const float* __restrict__ outW, const float* __restrict__ outb,
    float* __restrict__ out)
{
    const int tid  = blockIdx.x * 256 + threadIdx.x;
    const int b    = tid >> 4;     // batch element
    const int lane = tid & 15;     // 16 lanes per element

    // =================== ENCODER: gate-row-parallel (H=4) ===================
    // lane = k*4 + u : k in {i,f,g,o}, u = unit. Row r = lane of the (16,*) mats.
    const int u4 = lane & 3;
    const int kk = lane >> 2;
    const float sc = (kk == 2) ? S_TANH : S_SIG;
    const float Ak = (kk == 2) ? 2.0f : 1.0f;
    const float Bk = (kk == 2) ? -1.0f : 0.0f;

    float h0v[4] = {0.f, 0.f, 0.f, 0.f};
    float h1v[4] = {0.f, 0.f, 0.f, 0.f};
    float c0 = 0.f, c1 = 0.f;
    float fw0, fw1;

    {
        const int r = lane;
        float ew0 = eWih0[r] * sc;
        float eb0 = (ebih0[r] + ebhh0[r]) * sc;
        float eb1 = (ebih1[r] + ebhh1[r]) * sc;
        float ewh0[4], ewi1[4], ewh1[4];
#pragma unroll
        for (int j = 0; j < 4; ++j) {
            ewh0[j] = eWhh0[r * 4 + j] * sc;
            ewi1[j] = eWih1[r * 4 + j] * sc;
            ewh1[j] = eWhh1[r * 4 + j] * sc;
        }

        const float4* __restrict__ xq4 = (const float4*)(x + (long)b * T_N);
        float4 xq = xq4[0];

        auto estep = [&](float xc) {
            // L1 partial from previous h1 (independent of L0 chain)
            float p = eb1;
#pragma unroll
            for (int j = 0; j < 4; ++j) p = fmaf(ewh1[j], h1v[j], p);

            // L0 gate-row dot
            float g = fmaf(ew0, xc, eb0);
#pragma unroll
            for (int j = 0; j < 4; ++j) g = fmaf(ewh0[j], h0v[j], g);
            float gate = act_ab(g, Ak, Bk);   // one exp2+rcp for all 16 gate rows
            float fv = __shfl(gate, u4 + 4, 16);
            float gv = __shfl(gate, u4 + 8, 16);
            float ov = __shfl(gate, u4 + 12, 16);
            c0 = fmaf(fv, c0, gate * gv);     // valid on lanes 0..3 (gate = i there)
            float h0u = ov * tanh_nat(c0);
#pragma unroll
            for (int j = 0; j < 4; ++j) h0v[j] = __shfl(h0u, j, 16);

            // L1 gate-row dot (post-broadcast half)
            float q = 0.f;
#pragma unroll
            for (int j = 0; j < 4; ++j) q = fmaf(ewi1[j], h0v[j], q);
            float g1 = p + q;
            float gate1 = act_ab(g1, Ak, Bk);
            fv = __shfl(gate1, u4 + 4, 16);
            gv = __shfl(gate1, u4 + 8, 16);
            ov = __shfl(gate1, u4 + 12, 16);
            c1 = fmaf(fv, c1, gate1 * gv);
            float h1u = ov * tanh_nat(c1);
#pragma unroll
            for (int j = 0; j < 4; ++j) h1v[j] = __shfl(h1u, j, 16);
        };

        for (int tb = 0; tb < T_N / 4; ++tb) {
            float4 xn = (tb + 1 < T_N / 4) ? xq4[tb + 1] : xq;  // prefetch
            estep(xq.x); estep(xq.y); estep(xq.z); estep(xq.w);
            xq = xn;
        }

        // fwd_out = h1 @ fc_W.T + fc_b   (computed uniformly on all lanes)
        fw0 = fcb[0];
        fw1 = fcb[1];
#pragma unroll
        for (int j = 0; j < 4; ++j) {
            fw0 = fmaf(fcW[j], h1v[j], fw0);
            fw1 = fmaf(fcW[4 + j], h1v[j], fw1);
        }
        if (lane == 0) {
            out[FWD_OFF + b * 2 + 0] = fw0;
            out[FWD_OFF + b * 2 + 1] = fw1;
        }
    }

    // =================== DECODER: unit-parallel (H=10) ===================
    // lane = unit (0..9 active; 10..15 shadow 9). State handoff in-register:
    // encoder kept unit-u state on lane u (u<4); h vectors are replicated.
    const int uc = (lane < 10) ? lane : 9;

    float wih0r[4], b0r[4], b1r[4];
    float whh0r[4][10], wih1r[4][10], whh1r[4][10];
#pragma unroll
    for (int k = 0; k < 4; ++k) {
        const int r = k * 10 + uc;
        const float sck = (k == 2) ? S_TANH : S_SIG;
        wih0r[k] = dWih0[r] * sck;
        b0r[k] = (dbih0[r] + dbhh0[r]) * sck;
        b1r[k] = (dbih1[r] + dbhh1[r]) * sck;
#pragma unroll
        for (int j = 0; j < 10; ++j) {
            whh0r[k][j] = dWhh0[r * 10 + j] * sck;
            wih1r[k][j] = dWih1[r * 10 + j] * sck;
            whh1r[k][j] = dWhh1[r * 10 + j] * sck;
        }
    }
    float outw[10];
#pragma unroll
    for (int j = 0; j < 10; ++j) outw[j] = outW[j];
    const float outb0 = outb[0];

    // Initial decoder state: encoder finals padded 4 -> 10 with zeros
    float dh0[10], dh1[10];
#pragma unroll
    for (int j = 0; j < 10; ++j) {
        dh0[j] = (j < 4) ? h0v[j] : 0.f;
        dh1[j] = (j < 4) ? h1v[j] : 0.f;
    }
    float dc0 = (lane < 4) ? c0 : 0.f;
    float dc1 = (lane < 4) ? c1 : 0.f;

    float my_noise = 0.f;

    for (int t = 0; t < T_N; ++t) {
        const float inp = dh1[0];

        // L1 partial from previous h1 (independent of L0 chain)
        float p1[4];
#pragma unroll
        for (int k = 0; k < 4; ++k) {
            p1[k] = b1r[k];
#pragma unroll
            for (int j = 0; j < 10; ++j) p1[k] = fmaf(whh1r[k][j], dh1[j], p1[k]);
        }

        // L0 gates
        float g[4];
#pragma unroll
        for (int k = 0; k < 4; ++k) {
            g[k] = fmaf(wih0r[k], inp, b0r[k]);
#pragma unroll
            for (int j = 0; j < 10; ++j) g[k] = fmaf(whh0r[k][j], dh0[j], g[k]);
        }
        float iv = sig_acc(g[0]), fv = sig_acc(g[1]), gv = tanh_acc(g[2]), ov = sig_acc(g[3]);
        dc0 = fmaf(fv, dc0, iv * gv);
        const float h0u = ov * tanh_nat(dc0);
#pragma unroll
        for (int j = 0; j < 10; ++j) dh0[j] = __shfl(h0u, j, 16);

        // L1 gates: separate accumulator for the post-broadcast half (latency)
#pragma unroll
        for (int k = 0; k < 4; ++k) {
            float q = 0.f;
#pragma unroll
            for (int j = 0; j < 10; ++j) q = fmaf(wih1r[k][j], dh0[j], q);
            p1[k] += q;
        }
        iv = sig_acc(p1[0]); fv = sig_acc(p1[1]); gv = tanh_acc(p1[2]); ov = sig_acc(p1[3]);
        dc1 = fmaf(fv, dc1, iv * gv);
        const float h1u = ov * tanh_nat(dc1);
#pragma unroll
        for (int j = 0; j < 10; ++j) dh1[j] = __shfl(h1u, j, 16);

        // noise_t = dec_out . out_W + out_b (uniform on all 16 lanes)
        float nz = outb0;
#pragma unroll
        for (int j = 0; j < 10; ++j) nz = fmaf(outw[j], dh1[j], nz);

        // lane u keeps t with t%16==u; flush coalesced every 16 steps
        my_noise = ((t & 15) == lane) ? nz : my_noise;
        if ((t & 15) == 15) {
            const int idx = b * T_N + (t - 15) + lane;
            out[NOISE_OFF + idx] = my_noise;
            float2 fin;
            fin.x = my_noise + fw0;
            fin.y = my_noise + fw1;
            ((float2*)out)[idx] = fin;
        }
    }
}

extern "C" void kernel_launch(void* const* d_in, const int* in_sizes, int n_in,
                              void* d_out, int out_size, void* d_ws, size_t ws_size,
                              hipStream_t stream) {
    const float* x     = (const float*)d_in[0];
    // d_in[1] = context (unused by the reference)
    const float* eWih0 = (const float*)d_in[2];
    const float* eWhh0 = (const float*)d_in[3];
    const float* ebih0 = (const float*)d_in[4];
    const float* ebhh0 = (const float*)d_in[5];
    const float* eWih1 = (const float*)d_in[6];
    const float* eWhh1 = (const float*)d_in[7];
    const float* ebih1 = (const float*)d_in[8];
    const float* ebhh1 = (const float*)d_in[9];
    const float* dWih0 = (const float*)d_in[10];
    const float* dWhh0 = (const float*)d_in[11];
    const float* dbih0 = (const float*)d_in[12];
    const float* dbhh0 = (const float*)d_in[13];
    const float* dWih1 = (const float*)d_in[14];
    const float* dWhh1 = (const float*)d_in[15];
    const float* dbih1 = (const float*)d_in[16];
    const float* dbhh1 = (const float*)d_in[17];
    const float* fcW   = (const float*)d_in[18];
    const float* fcb   = (const float*)d_in[19];
    const float* outW  = (const float*)d_in[20];
    const float* outb  = (const float*)d_in[21];

    float* out = (float*)d_out;

    // 4096 elems x 16 lanes = 65536 threads = 1024 waves = 1 wave/SIMD
    fused_kernel<<<dim3((B_N * 16) / 256), dim3(256), 0, stream>>>(
        x, eWih0, eWhh0, ebih0, ebhh0, eWih1, eWhh1, ebih1, ebhh1,
        dWih0, dWhh0, dbih0, dbhh0, dWih1, dWhh1, dbih1, dbhh1,
        fcW, fcb, outW, outb, out);
}